// Round 5
// baseline (77.002 us; speedup 1.0000x reference)
//
#include <hip/hip_runtime.h>
#include <hip/hip_bf16.h>
#include <stdint.h>

typedef __attribute__((ext_vector_type(8))) short short8;
typedef __attribute__((ext_vector_type(4))) float f32x4;

#define BSZ 512
#define DFIELD 16384
#define KSPLIT 48
#define KCHUNK 1024
#define BK 64
#define NKSTEP (KCHUNK / BK)   /* 16 */
#define NTILE 10
#define TSIZE (128 * 128)
#define SKEW 5
#define NPAIRS 130816.0f

__device__ __forceinline__ float bf2f(ushort u) {
    return __uint_as_float(((uint32_t)u) << 16);
}

__device__ __forceinline__ ushort f2bf(float f) {
    uint32_t u = __float_as_uint(f);
    uint32_t r = (u + 0x7fffu + ((u >> 16) & 1u)) >> 16;
    return (ushort)r;
}

__device__ __forceinline__ uint2 cvt_f4(float4 v) {
    uint2 r;
    asm("v_cvt_pk_bf16_f32 %0, %1, %2" : "=v"(r.x) : "v"(v.x), "v"(v.y));
    asm("v_cvt_pk_bf16_f32 %0, %1, %2" : "=v"(r.y) : "v"(v.z), "v"(v.w));
    return r;
}

// 128x128 upper-tri tiles, KSPLIT=48, TWO-DEEP register pipeline with
// named buffers (static indexing) + double-buffered LDS. Loads for step
// k+2 issue before the barrier that precedes CVTWR(k+1) -> sustained
// outstanding loads instead of burst-drain.
__global__ __launch_bounds__(256, 2) void gemm_kernel(
    const float* __restrict__ e, const float* __restrict__ a,
    const float* __restrict__ c, ushort* __restrict__ P) {
    // XCD-chunked swizzle: 480 blocks, 8 XCDs, 60 per XCD (bijective).
    const int bid = blockIdx.x;
    const int lb  = (bid & 7) * 60 + (bid >> 3);
    const int tile = lb / KSPLIT;
    const int ks   = lb % KSPLIT;
    int ti = 0, rem = tile;
    while (rem >= 4 - ti) { rem -= 4 - ti; ++ti; }
    const int tj = ti + rem;
    const bool diag = (ti == tj);
    const int brow = ti * 128, bcol = tj * 128;

    const int kbase = ks * KCHUNK;
    const float* X = (kbase < DFIELD) ? e : (kbase < 2 * DFIELD ? a : c);
    const int koff0 = kbase & (DFIELD - 1);

    __shared__ ushort As[2][128 * 64];
    __shared__ ushort Bs[2][128 * 64];

    const int t = threadIdx.x;
    const int lane = t & 63, wid = t >> 6;
    const int wr = (wid >> 1) * 64, wc = (wid & 1) * 64;
    const bool skipw = diag && (wr == 64) && (wc == 0);

    const int srow = t >> 3;
    const int sg   = t & 7;
    const float* pa = X + (size_t)(brow + srow) * DFIELD + koff0 + sg * 8;
    const float* pb = X + (size_t)(bcol + srow) * DFIELD + koff0 + sg * 8;

    const f32x4 zero = {0.f, 0.f, 0.f, 0.f};
    f32x4 acc[4][4];
#pragma unroll
    for (int m = 0; m < 4; ++m)
#pragma unroll
        for (int n = 0; n < 4; ++n) acc[m][n] = zero;

    float4 ra0[8], rb0[8], ra1[8], rb1[8];

    auto LOAD = [&](int kk, float4* r_a, float4* r_b) {
#pragma unroll
        for (int rep = 0; rep < 4; ++rep) {
            const float* p = pa + (size_t)(rep * 32) * DFIELD + kk;
            r_a[2 * rep]     = reinterpret_cast<const float4*>(p)[0];
            r_a[2 * rep + 1] = reinterpret_cast<const float4*>(p)[1];
        }
        if (!diag) {
#pragma unroll
            for (int rep = 0; rep < 4; ++rep) {
                const float* p = pb + (size_t)(rep * 32) * DFIELD + kk;
                r_b[2 * rep]     = reinterpret_cast<const float4*>(p)[0];
                r_b[2 * rep + 1] = reinterpret_cast<const float4*>(p)[1];
            }
        }
    };
    auto CVTWR = [&](const float4* r_a, const float4* r_b, int buf) {
#pragma unroll
        for (int rep = 0; rep < 4; ++rep) {
            const int r = srow + rep * 32;
            uint2 w0 = cvt_f4(r_a[2 * rep]);
            uint2 w1 = cvt_f4(r_a[2 * rep + 1]);
            uint4 w = {w0.x, w0.y, w1.x, w1.y};
            const int g = sg ^ (r & 7);
            *reinterpret_cast<uint4*>(&As[buf][r * 64 + g * 8]) = w;
        }
        if (!diag) {
#pragma unroll
            for (int rep = 0; rep < 4; ++rep) {
                const int r = srow + rep * 32;
                uint2 w0 = cvt_f4(r_b[2 * rep]);
                uint2 w1 = cvt_f4(r_b[2 * rep + 1]);
                uint4 w = {w0.x, w0.y, w1.x, w1.y};
                const int g = sg ^ (r & 7);
                *reinterpret_cast<uint4*>(&Bs[buf][r * 64 + g * 8]) = w;
            }
        }
    };
    auto MFMA = [&](int buf) {
        if (skipw) return;
        const ushort* Asrc = As[buf];
        const ushort* Bsrc = diag ? As[buf] : Bs[buf];
#pragma unroll
        for (int half = 0; half < 2; ++half) {
            short8 af[4], bfv[4];
            const int kq = half * 4 + (lane >> 4);
#pragma unroll
            for (int m = 0; m < 4; ++m) {
                const int row = wr + m * 16 + (lane & 15);
                const int g = kq ^ (row & 7);
                af[m] = *reinterpret_cast<const short8*>(&Asrc[row * 64 + g * 8]);
            }
#pragma unroll
            for (int n = 0; n < 4; ++n) {
                const int row = wc + n * 16 + (lane & 15);
                const int g = kq ^ (row & 7);
                bfv[n] = *reinterpret_cast<const short8*>(&Bsrc[row * 64 + g * 8]);
            }
#pragma unroll
            for (int m = 0; m < 4; ++m)
#pragma unroll
                for (int n = 0; n < 4; ++n)
                    acc[m][n] = __builtin_amdgcn_mfma_f32_16x16x32_bf16(
                        af[m], bfv[n], acc[m][n], 0, 0, 0);
        }
    };

    // Prologue: fill both reg buffers, stage step 0 into LDS buf0.
    LOAD(0 * BK, ra0, rb0);
    LOAD(1 * BK, ra1, rb1);
    CVTWR(ra0, rb0, 0);     // buf0 = step 0 (vmcnt leaves step-1 loads in flight)
    __syncthreads();

    // Steady state: buf0 holds even steps, buf1 odd steps.
#pragma unroll 1
    for (int kt = 0; kt < NKSTEP; kt += 2) {
        // even step kt: compute buf0
        if (kt + 2 < NKSTEP) LOAD((kt + 2) * BK, ra0, rb0);
        MFMA(0);
        CVTWR(ra1, rb1, 1);                 // step kt+1 -> buf1
        __syncthreads();
        // odd step kt+1: compute buf1
        if (kt + 3 < NKSTEP) LOAD((kt + 3) * BK, ra1, rb1);
        MFMA(1);
        if (kt + 2 < NKSTEP) CVTWR(ra0, rb0, 0);  // step kt+2 -> buf0
        __syncthreads();
    }

    if (!skipw) {
        ushort* Pk = P + (size_t)(tile * KSPLIT + ks) * TSIZE;
        const int ci = (lane >> 4) * 4, cj = lane & 15;
#pragma unroll
        for (int m = 0; m < 4; ++m)
#pragma unroll
            for (int n = 0; n < 4; ++n)
#pragma unroll
                for (int r = 0; r < 4; ++r) {
                    const int li = wr + m * 16 + ci + r;
                    const int lj = wc + n * 16 + cj;
                    const int pr = (li + SKEW * ks) & 127;
                    Pk[pr * 128 + lj] = f2bf(acc[m][n][r]);
                }
    }
}

// Collapse 48 bf16 slices -> fp32 G[10][128][128]; DIAG inline. 320 blocks.
__global__ __launch_bounds__(256) void reducek_kernel(
    const ushort* __restrict__ P, float* __restrict__ G, float* __restrict__ DIAG) {
    const int t = threadIdx.x;
    const int tile  = blockIdx.x >> 5;   // 10 tiles x 32 chunks
    const int chunk = blockIdx.x & 31;
    const int li  = chunk * 4 + (t >> 6);
    const int ljq = (t & 63) * 2;
    float s0 = 0.f, s1 = 0.f;
    const ushort* base = P + (size_t)tile * KSPLIT * TSIZE + ljq;
#pragma unroll 8
    for (int k = 0; k < KSPLIT; ++k) {
        const int pr = (li + SKEW * k) & 127;
        const uint v = *reinterpret_cast<const uint*>(base + (size_t)k * TSIZE + pr * 128);
        s0 += bf2f((ushort)(v & 0xffff));
        s1 += bf2f((ushort)(v >> 16));
    }
    float2 g = {s0, s1};
    *reinterpret_cast<float2*>(&G[(size_t)tile * TSIZE + li * 128 + ljq]) = g;
    int dti = -1;
    if (tile == 0) dti = 0; else if (tile == 4) dti = 1;
    else if (tile == 7) dti = 2; else if (tile == 9) dti = 3;
    if (dti >= 0 && ljq == (li & ~1))
        DIAG[dti * 128 + li] = (li & 1) ? s1 : s0;
}

__global__ __launch_bounds__(256) void pair_kernel(
    const float* __restrict__ G, const float* __restrict__ DIAG,
    const int* __restrict__ tg, float* __restrict__ LP) {
    const int t = threadIdx.x;
    const int gid = blockIdx.x * 256 + t;   // 128 blocks
    const int i = gid >> 6;
    const int j0 = (gid & 63) * 8;
    float local = 0.f;
    if (j0 + 7 > i) {
        const int ti2 = i >> 7, tj2 = j0 >> 7;
        const int tidx = (ti2 * (9 - ti2)) / 2 + (tj2 - ti2);
        const int li = i & 127, lj0 = j0 & 127;
        const float* g = G + (size_t)tidx * TSIZE + li * 128 + lj0;
        float4 g0 = reinterpret_cast<const float4*>(g)[0];
        float4 g1 = reinterpret_cast<const float4*>(g)[1];
        float gv[8] = {g0.x, g0.y, g0.z, g0.w, g1.x, g1.y, g1.z, g1.w};
        const float di = DIAG[i];
        const int lbl = tg[i];
#pragma unroll
        for (int u = 0; u < 8; ++u) {
            const int j = j0 + u;
            if (j > i) {
                const float d = (di + DIAG[j] - 2.f * gv[u]) * (1.f / 16384.f);
                local += (lbl == tg[j]) ? d : fmaxf(1.f - d, 0.f);
            }
        }
    }
#pragma unroll
    for (int off = 32; off; off >>= 1) local += __shfl_down(local, off, 64);
    __shared__ float red[4];
    const int lane = t & 63, wid = t >> 6;
    if (lane == 0) red[wid] = local;
    __syncthreads();
    if (t == 0) LP[blockIdx.x] = red[0] + red[1] + red[2] + red[3];
}

__global__ void final_kernel(const float* __restrict__ LP, float* __restrict__ out) {
    const int t = threadIdx.x;  // 128
    float v = LP[t];
#pragma unroll
    for (int off = 32; off; off >>= 1) v += __shfl_down(v, off, 64);
    __shared__ float red[2];
    if ((t & 63) == 0) red[t >> 6] = v;
    __syncthreads();
    if (t == 0) out[0] = (red[0] + red[1]) * (1.f / NPAIRS);
}

extern "C" void kernel_launch(void* const* d_in, const int* in_sizes, int n_in,
                              void* d_out, int out_size, void* d_ws, size_t ws_size,
                              hipStream_t stream) {
    const float* e  = (const float*)d_in[0];
    const float* a  = (const float*)d_in[1];
    const float* c  = (const float*)d_in[2];
    const int*   tg = (const int*)d_in[3];

    ushort* P    = (ushort*)d_ws;                                   // 15.7 MB
    float*  G    = (float*)((char*)d_ws + (size_t)NTILE * KSPLIT * TSIZE * 2);
    float*  DIAG = G + (size_t)NTILE * TSIZE;
    float*  LP   = DIAG + BSZ;
    float*  out  = (float*)d_out;

    gemm_kernel<<<dim3(NTILE * KSPLIT), dim3(256), 0, stream>>>(e, a, c, P);
    reducek_kernel<<<dim3(320), dim3(256), 0, stream>>>(P, G, DIAG);
    pair_kernel<<<dim3(128), dim3(256), 0, stream>>>(G, DIAG, tg, LP);
    final_kernel<<<dim3(1), dim3(128), 0, stream>>>(LP, out);
}

// Round 6
// 55.780 us; speedup vs baseline: 1.3805x; 1.3805x over previous
//
#include <hip/hip_runtime.h>
#include <hip/hip_bf16.h>
#include <stdint.h>

typedef __attribute__((ext_vector_type(8))) short short8;
typedef __attribute__((ext_vector_type(4))) float f32x4;

#define BSZ 512
#define KTOT 49152
#define KSPLIT 48
#define KCHUNK 1024
#define BK 64
#define NKSTEP (KCHUNK / BK)   /* 16 */
#define NTILE 10
#define TSIZE (128 * 128)
#define SKEW 5
#define NPAIRS 130816.0f

__device__ __forceinline__ float bf2f(ushort u) {
    return __uint_as_float(((uint32_t)u) << 16);
}

__device__ __forceinline__ ushort f2bf(float f) {
    uint32_t u = __float_as_uint(f);
    uint32_t r = (u + 0x7fffu + ((u >> 16) & 1u)) >> 16;
    return (ushort)r;
}

__device__ __forceinline__ uint2 cvt_f4(float4 v) {
    uint2 r;
    asm("v_cvt_pk_bf16_f32 %0, %1, %2" : "=v"(r.x) : "v"(v.x), "v"(v.y));
    asm("v_cvt_pk_bf16_f32 %0, %1, %2" : "=v"(r.y) : "v"(v.z), "v"(v.w));
    return r;
}

__device__ __forceinline__ void gload_lds16(const ushort* g, ushort* l) {
    __builtin_amdgcn_global_load_lds(
        (const __attribute__((address_space(1))) uint32_t*)g,
        (__attribute__((address_space(3))) uint32_t*)l, 16, 0, 0);
}

// ---- Pass 1: fp32 fields -> single bf16 matrix W[512][49152] ----
__global__ __launch_bounds__(256) void convert_kernel(
    const float* __restrict__ e, const float* __restrict__ a,
    const float* __restrict__ c, ushort* __restrict__ W) {
    const int g = blockIdx.x * 256 + threadIdx.x;   // 12288 blocks
    const int E = g * 8;                            // elem base within 3*8.39M
    const int f = E >> 23;                          // field (8388608 elems each)
    const int rem = E & 8388607;
    const int row = rem >> 14, col = rem & 16383;
    const float* src = (f == 0) ? e : (f == 1 ? a : c);
    float4 v0 = reinterpret_cast<const float4*>(src + rem)[0];
    float4 v1 = reinterpret_cast<const float4*>(src + rem)[1];
    uint2 w0 = cvt_f4(v0), w1 = cvt_f4(v1);
    uint4 w = {w0.x, w0.y, w1.x, w1.y};
    *reinterpret_cast<uint4*>(&W[(size_t)row * KTOT + f * 16384 + col]) = w;
}

// ---- Pass 2: m97-structure GEMM. 128^2 upper-tri tiles, KSPLIT=48,
// global_load_lds w=16 with pre-swizzled per-lane SOURCE + linear LDS dest,
// swizzled fragment reads (rule #21 pattern). ----
__global__ __launch_bounds__(256, 2) void gemm_kernel(
    const ushort* __restrict__ W, ushort* __restrict__ P) {
    const int tile = blockIdx.x / KSPLIT;
    const int ks   = blockIdx.x % KSPLIT;
    int ti = 0, rem = tile;
    while (rem >= 4 - ti) { rem -= 4 - ti; ++ti; }
    const int tj = ti + rem;
    const bool diag = (ti == tj);
    const int brow = ti * 128, bcol = tj * 128;
    const int kbase = ks * KCHUNK;

    __shared__ ushort As[128 * 64];
    __shared__ ushort Bs[128 * 64];

    const int t = threadIdx.x;
    const int lane = t & 63, wid = t >> 6;
    const int wr = (wid >> 1) * 64, wc = (wid & 1) * 64;
    const bool skipw = diag && (wr == 64) && (wc == 0);

    // staging geometry: issue i covers rows [i*32, i*32+32), 128 B/row.
    // thread t: row-in-issue = t>>3, slot s = t&7. LDS is linear; the
    // SOURCE k-granule is pre-swizzled so LDS(row, slot) holds granule
    // slot ^ (row&7), matching the fragment-read swizzle.
    const int grow = t >> 3, s = t & 7;
    const int swz = (s ^ (grow & 7)) * 8;   // bf16 elems
    const ushort* pa = W + (size_t)(brow + grow) * KTOT + kbase + swz;
    const ushort* pb = W + (size_t)(bcol + grow) * KTOT + kbase + swz;
    ushort* la = &As[t * 8];
    ushort* lb = &Bs[t * 8];

    const f32x4 zero = {0.f, 0.f, 0.f, 0.f};
    f32x4 acc[4][4];
#pragma unroll
    for (int m = 0; m < 4; ++m)
#pragma unroll
        for (int n = 0; n < 4; ++n) acc[m][n] = zero;

#pragma unroll 1
    for (int kt = 0; kt < NKSTEP; ++kt) {
        const int kk = kt * BK;
#pragma unroll
        for (int i = 0; i < 4; ++i)
            gload_lds16(pa + (size_t)(i * 32) * KTOT + kk, la + i * 2048);
        if (!diag) {
#pragma unroll
            for (int i = 0; i < 4; ++i)
                gload_lds16(pb + (size_t)(i * 32) * KTOT + kk, lb + i * 2048);
        }
        __syncthreads();   // drains vmcnt -> LDS valid
        if (!skipw) {
            const ushort* Bsrc = diag ? As : Bs;
#pragma unroll
            for (int half = 0; half < 2; ++half) {
                short8 af[4], bfv[4];
                const int kq = half * 4 + (lane >> 4);
#pragma unroll
                for (int m = 0; m < 4; ++m) {
                    const int row = wr + m * 16 + (lane & 15);
                    const int g = kq ^ (row & 7);
                    af[m] = *reinterpret_cast<const short8*>(&As[row * 64 + g * 8]);
                }
#pragma unroll
                for (int n = 0; n < 4; ++n) {
                    const int row = wc + n * 16 + (lane & 15);
                    const int g = kq ^ (row & 7);
                    bfv[n] = *reinterpret_cast<const short8*>(&Bsrc[row * 64 + g * 8]);
                }
#pragma unroll
                for (int m = 0; m < 4; ++m)
#pragma unroll
                    for (int n = 0; n < 4; ++n)
                        acc[m][n] = __builtin_amdgcn_mfma_f32_16x16x32_bf16(
                            af[m], bfv[n], acc[m][n], 0, 0, 0);
            }
        }
        __syncthreads();   // protect LDS from next iter's staging
    }

    if (!skipw) {
        ushort* Pk = P + (size_t)(tile * KSPLIT + ks) * TSIZE;
        const int ci = (lane >> 4) * 4, cj = lane & 15;
#pragma unroll
        for (int m = 0; m < 4; ++m)
#pragma unroll
            for (int n = 0; n < 4; ++n)
#pragma unroll
                for (int r = 0; r < 4; ++r) {
                    const int li = wr + m * 16 + ci + r;
                    const int lj = wc + n * 16 + cj;
                    const int pr = (li + SKEW * ks) & 127;   // de-alias channels
                    Pk[pr * 128 + lj] = f2bf(acc[m][n][r]);
                }
    }
}

// Collapse 48 bf16 slices -> fp32 G[10][128][128]; DIAG inline. 320 blocks.
__global__ __launch_bounds__(256) void reducek_kernel(
    const ushort* __restrict__ P, float* __restrict__ G, float* __restrict__ DIAG) {
    const int t = threadIdx.x;
    const int tile  = blockIdx.x >> 5;   // 10 tiles x 32 chunks
    const int chunk = blockIdx.x & 31;
    const int li  = chunk * 4 + (t >> 6);
    const int ljq = (t & 63) * 2;
    float s0 = 0.f, s1 = 0.f;
    const ushort* base = P + (size_t)tile * KSPLIT * TSIZE + ljq;
#pragma unroll 8
    for (int k = 0; k < KSPLIT; ++k) {
        const int pr = (li + SKEW * k) & 127;
        const uint v = *reinterpret_cast<const uint*>(base + (size_t)k * TSIZE + pr * 128);
        s0 += bf2f((ushort)(v & 0xffff));
        s1 += bf2f((ushort)(v >> 16));
    }
    float2 g = {s0, s1};
    *reinterpret_cast<float2*>(&G[(size_t)tile * TSIZE + li * 128 + ljq]) = g;
    int dti = -1;
    if (tile == 0) dti = 0; else if (tile == 4) dti = 1;
    else if (tile == 7) dti = 2; else if (tile == 9) dti = 3;
    if (dti >= 0 && ljq == (li & ~1))
        DIAG[dti * 128 + li] = (li & 1) ? s1 : s0;
}

__global__ __launch_bounds__(256) void pair_kernel(
    const float* __restrict__ G, const float* __restrict__ DIAG,
    const int* __restrict__ tg, float* __restrict__ LP) {
    const int t = threadIdx.x;
    const int gid = blockIdx.x * 256 + t;   // 128 blocks
    const int i = gid >> 6;
    const int j0 = (gid & 63) * 8;
    float local = 0.f;
    if (j0 + 7 > i) {
        const int ti2 = i >> 7, tj2 = j0 >> 7;
        const int tidx = (ti2 * (9 - ti2)) / 2 + (tj2 - ti2);
        const int li = i & 127, lj0 = j0 & 127;
        const float* g = G + (size_t)tidx * TSIZE + li * 128 + lj0;
        float4 g0 = reinterpret_cast<const float4*>(g)[0];
        float4 g1 = reinterpret_cast<const float4*>(g)[1];
        float gv[8] = {g0.x, g0.y, g0.z, g0.w, g1.x, g1.y, g1.z, g1.w};
        const float di = DIAG[i];
        const int lbl = tg[i];
#pragma unroll
        for (int u = 0; u < 8; ++u) {
            const int j = j0 + u;
            if (j > i) {
                const float d = (di + DIAG[j] - 2.f * gv[u]) * (1.f / 16384.f);
                local += (lbl == tg[j]) ? d : fmaxf(1.f - d, 0.f);
            }
        }
    }
#pragma unroll
    for (int off = 32; off; off >>= 1) local += __shfl_down(local, off, 64);
    __shared__ float red[4];
    const int lane = t & 63, wid = t >> 6;
    if (lane == 0) red[wid] = local;
    __syncthreads();
    if (t == 0) LP[blockIdx.x] = red[0] + red[1] + red[2] + red[3];
}

__global__ void final_kernel(const float* __restrict__ LP, float* __restrict__ out) {
    const int t = threadIdx.x;  // 128
    float v = LP[t];
#pragma unroll
    for (int off = 32; off; off >>= 1) v += __shfl_down(v, off, 64);
    __shared__ float red[2];
    if ((t & 63) == 0) red[t >> 6] = v;
    __syncthreads();
    if (t == 0) out[0] = (red[0] + red[1]) * (1.f / NPAIRS);
}

extern "C" void kernel_launch(void* const* d_in, const int* in_sizes, int n_in,
                              void* d_out, int out_size, void* d_ws, size_t ws_size,
                              hipStream_t stream) {
    const float* e  = (const float*)d_in[0];
    const float* a  = (const float*)d_in[1];
    const float* c  = (const float*)d_in[2];
    const int*   tg = (const int*)d_in[3];

    ushort* W    = (ushort*)d_ws;                                  // 50.33 MB
    ushort* P    = W + (size_t)BSZ * KTOT;                         // 15.73 MB
    float*  G    = (float*)(P + (size_t)NTILE * KSPLIT * TSIZE);   // 0.66 MB
    float*  DIAG = G + (size_t)NTILE * TSIZE;
    float*  LP   = DIAG + BSZ;
    float*  out  = (float*)d_out;

    convert_kernel<<<dim3(12288), dim3(256), 0, stream>>>(e, a, c, W);
    gemm_kernel<<<dim3(NTILE * KSPLIT), dim3(256), 0, stream>>>(W, P);
    reducek_kernel<<<dim3(320), dim3(256), 0, stream>>>(P, G, DIAG);
    pair_kernel<<<dim3(128), dim3(256), 0, stream>>>(G, DIAG, tg, LP);
    final_kernel<<<dim3(1), dim3(128), 0, stream>>>(LP, out);
}